// Round 2
// baseline (415.171 us; speedup 1.0000x reference)
//
#include <hip/hip_runtime.h>

// R5: 32x32x16 f16 MFMA band-Toeplitz FIR.
//   out[r, t] = sum_j e[r, j] * g[j - t],  g[k] = h[412-k], e = reflect-extended row.
// Changes vs R4 (186us, VGPR=72 proved A-frags were NOT register-resident -> per-tile
// scalar ds_read_u16 A-gathers dominated the LDS pipe):
//   - mfma_f32_32x32x16_f16: same B bytes per MFMA, 2x FLOP -> per-FLOP LDS traffic halves.
//   - q-outer / tile-inner (T=3 or 2 tiles per wave): A frag loaded once per q, used 2T x.
//   - A as 8 shifted rows arow[r][v] = g[v-24-r]; lane m reads row m&7 at
//     v = 16q + 8*(l>>5) - 8*(m>>3) + 24 -> always one aligned ds_read_b128, no gathers.
//   - hi/lo filter split (exact to 2^-22) accumulates into the SAME acc (two MFMAs).
//   - e-tile: 32 rows x 96 16B-slots, slot ^= (row&7) swizzle -> 2-way max (free).
//   - Block: 32 channels x 320 outputs (10 tiles); waves take 3/3/2/2 tiles.
//     LDS = 49152 + 15104 = 64256 B -> 2 blocks/CU.
// Per-CU budget: MFMA ~71k cyc, LDS ~103k cyc, HBM 324MB chip (~51us) -> expect ~100us.

#define T_LEN 10000
#define N_H   413
#define SHIFT 206
#define CB    320            // outputs per block = 10 tiles of 32
#define NSEG  32             // ceil(10000/320)
#define NSLOT 96             // 16B slots per e-row (span 768 = CB + 448)
#define ROWH  (NSLOT * 8)    // halfs per e-row
#define NQ    28             // K-chunks of 16 taps (span 448 >= 413 + 31)
#define AROWL 472            // halfs per A row: v in [0,472), arow[r][v] = g[v-24-r]

typedef _Float16 v8h   __attribute__((ext_vector_type(8)));
typedef float    v16f  __attribute__((ext_vector_type(16)));
typedef float    v4f   __attribute__((ext_vector_type(4)));
typedef float    f32x2 __attribute__((ext_vector_type(2)));

template <int NT>
__device__ __forceinline__ void compute_tiles(
    const _Float16* __restrict__ lds_e, const _Float16* __restrict__ a0,
    const _Float16* __restrict__ a1, float* __restrict__ out,
    int t0b, int r0, int tbeg, int l) {
    const int n   = l & 31;                 // signal row (B col, D col) AND filter row m
    const int hh  = l >> 5;                 // k-half selector
    const int vv0 = 24 + 8 * hh - 8 * (n >> 3);   // aligned A base, in [0,32]
    const v8h* __restrict__ pah = (const v8h*)(a0 + (n & 7) * AROWL + vv0);
    const v8h* __restrict__ pal = (const v8h*)(a1 + (n & 7) * AROWL + vv0);
    const char* __restrict__ eb = (const char*)lds_e + n * (ROWH * 2);
    const int nx = n & 7;

    v16f acc[NT];
    #pragma unroll
    for (int t = 0; t < NT; ++t) acc[t] = (v16f)(0.0f);

    #pragma unroll
    for (int q = 0; q < NQ; ++q) {
        const v8h ah = pah[2 * q];          // A_q hi: g[16q + k - m], k = 8*hh + i
        const v8h al = pal[2 * q];          // A_q lo
        #pragma unroll
        for (int t = 0; t < NT; ++t) {
            const int s = 4 * (tbeg + t) + hh + 2 * q;      // 16B slot, < 96
            const v8h b = *(const v8h*)(eb + ((s ^ nx) << 4));
            acc[t] = __builtin_amdgcn_mfma_f32_32x32x16_f16(ah, b, acc[t], 0, 0, 0);
            acc[t] = __builtin_amdgcn_mfma_f32_32x32x16_f16(al, b, acc[t], 0, 0, 0);
        }
    }

    // D: col = lane&31 -> channel row; m = (reg&3) + 8*(reg>>2) + 4*hh -> 4 groups of
    // 4 consecutive t per lane -> dwordx4 stores, guarded for the 10000-tail.
    #pragma unroll
    for (int t = 0; t < NT; ++t) {
        const int tt = tbeg + t;
        float* __restrict__ orow =
            out + (size_t)(r0 + n) * T_LEN + (t0b + 32 * tt + 4 * hh);
        #pragma unroll
        for (int g = 0; g < 4; ++g) {
            const int tg = t0b + 32 * tt + 8 * g + 4 * hh;
            if (tg < T_LEN) {
                *(v4f*)(orow + 8 * g) =
                    (v4f){acc[t][4*g], acc[t][4*g+1], acc[t][4*g+2], acc[t][4*g+3]};
            }
        }
    }
}

__global__ __launch_bounds__(256, 2) void FilterBank_20624432955781_kernel(
    const float* __restrict__ x, const float* __restrict__ h, float* __restrict__ out) {
    __shared__ alignas(16) _Float16 lds_e[32 * ROWH];        // 49152 B, swizzled slots
    __shared__ alignas(16) _Float16 arow[2][8][AROWL];       // 15104 B (hi, lo)

    const int tid = threadIdx.x;
    const int t0b = blockIdx.x * CB;
    const int r0  = blockIdx.y * 32;

    // ---- stage A: arow[a][r][v] = split(g[v - 24 - r]), g[k] = h[412-k] ----
    for (int z = tid; z < 8 * AROWL; z += 256) {
        const int r = z / AROWL, vv = z - r * AROWL;
        const int idx = 436 + r - vv;                        // h index
        const float gv = (idx >= 0 && idx < N_H) ? h[idx] : 0.0f;
        const _Float16 hi = (_Float16)gv;
        arow[0][r][vv] = hi;
        arow[1][r][vv] = (_Float16)(gv - (float)hi);
    }

    // ---- stage e: 32 rows, 8 threads/row, 12 slots each; reflect_limited edges ----
    {
        const int rr = tid >> 3;
        const float* __restrict__ xr = x + (size_t)(r0 + rr) * T_LEN;
        _Float16* __restrict__ erow = lds_e + rr * ROWH;
        const int rx = rr & 7;
        #pragma unroll
        for (int it = 0; it < 12; ++it) {
            const int c8 = (tid & 7) + 8 * it;               // slot 0..95
            const int j0 = t0b + c8 * 8;                     // global e index base
            float v[8];
            if (j0 >= SHIFT && j0 + 8 <= T_LEN + SHIFT) {    // interior fast path
                const f32x2* xp = (const f32x2*)(xr + (j0 - SHIFT));
                #pragma unroll
                for (int p = 0; p < 4; ++p) { f32x2 t2 = xp[p]; v[2*p] = t2.x; v[2*p+1] = t2.y; }
            } else {
                #pragma unroll
                for (int k = 0; k < 8; ++k) {
                    const int j = j0 + k;
                    if (j < SHIFT)              v[k] = 2.0f * xr[0] - xr[SHIFT - j];
                    else if (j < T_LEN + SHIFT) v[k] = xr[j - SHIFT];
                    else                        v[k] = 2.0f * xr[T_LEN - 1] - xr[2 * T_LEN + SHIFT - 2 - j];
                    // max staged j = 31*320 + 767 = 10687 -> mirror idx >= 9517: in-bounds.
                }
            }
            v8h hv;
            #pragma unroll
            for (int k = 0; k < 8; ++k) hv[k] = (_Float16)v[k];
            *(v8h*)(erow + ((c8 ^ rx) * 8)) = hv;
        }
    }
    __syncthreads();

    const int l  = tid & 63;
    const int wv = tid >> 6;
    const _Float16* a0 = &arow[0][0][0];
    const _Float16* a1 = &arow[1][0][0];
    if (wv < 2) compute_tiles<3>(lds_e, a0, a1, out, t0b, r0, 3 * wv, l);
    else        compute_tiles<2>(lds_e, a0, a1, out, t0b, r0, 6 + 2 * (wv - 2), l);
}

extern "C" void kernel_launch(void* const* d_in, const int* in_sizes, int n_in,
                              void* d_out, int out_size, void* d_ws, size_t ws_size,
                              hipStream_t stream) {
    const float* x = (const float*)d_in[0];   // [64,64,10000] fp32
    const float* h = (const float*)d_in[1];   // [413] fp32
    float* out = (float*)d_out;               // [64,64,10000] fp32
    dim3 grid(NSEG, 64 * 64 / 32);            // 32 t-segments x 128 channel-blocks
    FilterBank_20624432955781_kernel<<<grid, dim3(256), 0, stream>>>(x, h, out);
}

// Round 3
// 374.045 us; speedup vs baseline: 1.1100x; 1.1100x over previous
//
#include <hip/hip_runtime.h>

// R6: 16-channel blocks, paired-tile 32x32 MFMA, 3 blocks/CU.
//   out[r, t] = sum_j e[r, j] * g[j - t],  g[k] = h[412-k], e = reflect-extended row.
// R5 post-mortem: 233us with MfmaUtil 13 / VALU 11 / HBM 20 / Occ 16.5% -> stall-bound.
//   64.5KB LDS capped residency at 2 blocks/CU; stage->barrier->compute serial chain had
//   nothing to overlap it; 11.9M bank-conflict cycles; 3/3/2/2 wave imbalance.
// R6 changes:
//   - 16 channels/block; B's 32 cols = (channel, tile-half): B[k,n] = e[n&15][.. +32*(n>>4)+k].
//     Same MFMA count/efficiency, HALF the e-tile -> LDS 45056 B -> 3 blocks/CU (12 waves),
//     cross-block stage/compute stagger.
//   - CB=512 -> 8 tile-pairs, exactly 2 per wave (balanced); A frags amortized over both,
//     B frag reused by hi+lo MFMAs; MFMAs interleaved across the 2 acc chains.
//   - Bank conflicts fixed by stride, no xor: e-row stride 936 halfs (468 dw == 20 mod 32,
//     odd group rotation -> each 8-lane run covers all 8 4-dw groups); A stride 236 dw == 12.
//   - Staging: 16 thr/row, 16-float chunks (64 B contiguous per thread), f32x2 loads
//     (8B-aligned since SHIFT=206 == 2 mod 8), 2x ds_write_b128 per chunk.
// Budget/CU: MFMA 29us, LDS ~44us, HBM ~51us; 3-block overlap -> expect ~110-140us.

#define T_LEN 10000
#define N_H   413
#define SHIFT 206
#define CB    512            // outputs per block = 8 pairs of two 32-wide t-tiles
#define NSEG  20             // ceil(10000/512); last block: 272 outputs -> NP=5
#define ROWH  936            // halfs per e-row (928 staged + 8 pad)
#define NQ    28             // K-chunks of 16 taps
#define AROWL 472            // halfs per A row: arow[a][r][v] = split(g[v-24-r])

typedef _Float16 v8h   __attribute__((ext_vector_type(8)));
typedef float    v16f  __attribute__((ext_vector_type(16)));
typedef float    v4f   __attribute__((ext_vector_type(4)));
typedef float    f32x2 __attribute__((ext_vector_type(2)));

__device__ __forceinline__ void store_col(float* __restrict__ orow, const v16f& acc,
                                          int tbase, int guard_needed) {
    // D col = lane&31 -> (ch, th); row m = (reg&3) + 8*(reg>>2) + 4*hh -> t offset.
    #pragma unroll
    for (int g = 0; g < 4; ++g) {
        if (!guard_needed || (tbase + 8 * g) < T_LEN) {
            *(v4f*)(orow + 8 * g) =
                (v4f){acc[4*g], acc[4*g+1], acc[4*g+2], acc[4*g+3]};
        }
    }
}

__global__ __launch_bounds__(256, 3) void FilterBank_20624432955781_kernel(
    const float* __restrict__ x, const float* __restrict__ h, float* __restrict__ out) {
    __shared__ alignas(16) _Float16 lds_e[16 * ROWH];     // 29952 B
    __shared__ alignas(16) _Float16 arow[2][8][AROWL];    // 15104 B (hi, lo)

    const int tid = threadIdx.x;
    const int t0b = blockIdx.x * CB;
    const int r0  = blockIdx.y * 16;

    // ---- stage A: arow[a][r][v] = split(g[v-24-r]), g[k] = h[412-k] ----
    for (int z = tid; z < 8 * AROWL; z += 256) {
        const int r = z / AROWL, vv = z - r * AROWL;
        const int idx = 436 + r - vv;
        const float gv = (idx >= 0 && idx < N_H) ? h[idx] : 0.0f;
        const _Float16 hi = (_Float16)gv;
        arow[0][r][vv] = hi;
        arow[1][r][vv] = (_Float16)(gv - (float)hi);
    }

    // ---- stage e: 16 rows x 58 chunks of 16 halfs; 16 threads/row ----
    {
        const int rr = tid >> 4;
        const int jt = tid & 15;
        const float* __restrict__ xr = x + (size_t)(r0 + rr) * T_LEN;
        _Float16* __restrict__ erow = lds_e + rr * ROWH;
        #pragma unroll
        for (int it = 0; it < 4; ++it) {
            const int c = jt + 16 * it;                  // chunk 0..57
            if (c < 58) {
                const int j0 = t0b + 16 * c;             // e-index of chunk start
                float v[16];
                if (j0 >= SHIFT && j0 + 16 <= T_LEN + SHIFT) {   // interior fast path
                    const f32x2* xp = (const f32x2*)(xr + (j0 - SHIFT));
                    #pragma unroll
                    for (int p = 0; p < 8; ++p) { f32x2 t2 = xp[p]; v[2*p] = t2.x; v[2*p+1] = t2.y; }
                } else {                                  // reflect_limited edges
                    #pragma unroll
                    for (int k = 0; k < 16; ++k) {
                        const int j = j0 + k;
                        if (j < SHIFT)              v[k] = 2.0f * xr[0] - xr[SHIFT - j];
                        else if (j < T_LEN + SHIFT) v[k] = xr[j - SHIFT];
                        else                        v[k] = 2.0f * xr[T_LEN - 1] - xr[2 * T_LEN + SHIFT - 2 - j];
                        // max staged j = 19*512 + 16*57 + 15 = 10655 -> mirror idx >= 9549: in-bounds.
                    }
                }
                v8h h0, h1;
                #pragma unroll
                for (int k = 0; k < 8; ++k) { h0[k] = (_Float16)v[k]; h1[k] = (_Float16)v[8 + k]; }
                *(v8h*)(erow + 16 * c)     = h0;          // slot 2c
                *(v8h*)(erow + 16 * c + 8) = h1;          // slot 2c+1
            }
        }
    }
    __syncthreads();

    const int l  = tid & 63;
    const int wv = tid >> 6;
    const int n  = l & 31;                 // A row m-shift index AND B col (ch, th)
    const int hh = l >> 5;                 // k-half selector
    const int ch = n & 15;
    const int th = n >> 4;
    const int vv0 = 24 + 8 * hh - 8 * (n >> 3);          // in [0,32], 16B-aligned
    const v8h* __restrict__ pah = (const v8h*)(&arow[0][n & 7][0] + vv0);
    const v8h* __restrict__ pal = (const v8h*)(&arow[1][n & 7][0] + vv0);
    const _Float16* __restrict__ ebase = lds_e + ch * ROWH + 32 * th + 8 * hh;

    const int n_out = T_LEN - t0b;                        // 512 for bx<19, else 272
    const int NP = (n_out < CB ? n_out + 63 : CB + 63) >> 6;   // tile-pairs: 8 or 5
    const int guard = (t0b + CB > T_LEN);

    int p = wv;
    if (p + 4 < NP) {
        // ---- dual-pair q-loop: A frags amortized, B reused by hi+lo ----
        const _Float16* __restrict__ eb0 = ebase + 64 * p;
        const _Float16* __restrict__ eb1 = ebase + 64 * (p + 4);
        v16f acc0 = (v16f)(0.0f), acc1 = (v16f)(0.0f);
        #pragma unroll
        for (int q = 0; q < NQ; ++q) {
            const v8h ah = pah[2 * q];                    // g[16q + k - m] (hi)
            const v8h al = pal[2 * q];                    // (lo)
            const v8h b0 = *(const v8h*)(eb0 + 16 * q);
            const v8h b1 = *(const v8h*)(eb1 + 16 * q);
            acc0 = __builtin_amdgcn_mfma_f32_32x32x16_f16(ah, b0, acc0, 0, 0, 0);
            acc1 = __builtin_amdgcn_mfma_f32_32x32x16_f16(ah, b1, acc1, 0, 0, 0);
            acc0 = __builtin_amdgcn_mfma_f32_32x32x16_f16(al, b0, acc0, 0, 0, 0);
            acc1 = __builtin_amdgcn_mfma_f32_32x32x16_f16(al, b1, acc1, 0, 0, 0);
        }
        {
            const int tb0 = t0b + 64 * p + 32 * th + 4 * hh;
            const int tb1 = t0b + 64 * (p + 4) + 32 * th + 4 * hh;
            float* orow = out + (size_t)(r0 + ch) * T_LEN;
            store_col(orow + tb0, acc0, tb0, guard);
            store_col(orow + tb1, acc1, tb1, guard);
        }
        p += 8;
    }
    for (; p < NP; p += 4) {
        // ---- tail: single-pair q-loop (last block only) ----
        const _Float16* __restrict__ eb0 = ebase + 64 * p;
        v16f acc0 = (v16f)(0.0f);
        #pragma unroll
        for (int q = 0; q < NQ; ++q) {
            const v8h ah = pah[2 * q];
            const v8h al = pal[2 * q];
            const v8h b0 = *(const v8h*)(eb0 + 16 * q);
            acc0 = __builtin_amdgcn_mfma_f32_32x32x16_f16(ah, b0, acc0, 0, 0, 0);
            acc0 = __builtin_amdgcn_mfma_f32_32x32x16_f16(al, b0, acc0, 0, 0, 0);
        }
        const int tb0 = t0b + 64 * p + 32 * th + 4 * hh;
        store_col(out + (size_t)(r0 + ch) * T_LEN + tb0, acc0, tb0, guard);
    }
}

extern "C" void kernel_launch(void* const* d_in, const int* in_sizes, int n_in,
                              void* d_out, int out_size, void* d_ws, size_t ws_size,
                              hipStream_t stream) {
    const float* x = (const float*)d_in[0];   // [64,64,10000] fp32
    const float* h = (const float*)d_in[1];   // [413] fp32
    float* out = (float*)d_out;               // [64,64,10000] fp32
    dim3 grid(NSEG, 64 * 64 / 16);            // 20 t-segments x 256 channel-blocks
    FilterBank_20624432955781_kernel<<<grid, dim3(256), 0, stream>>>(x, h, out);
}

// Round 4
// 334.481 us; speedup vs baseline: 1.2412x; 1.1183x over previous
//
#include <hip/hip_runtime.h>

// R7: persistent 16-channel blocks + register-prefetched staging (T14 async-STAGE).
//   out[r, t] = sum_j e[r, j] * g[j - t],  g[k] = h[412-k], e = reflect-extended row.
// R6 post-mortem: 189us, all pipes <25% -> latency-bound. 5120 one-shot blocks each:
//   A-rebuild (identical, 20x/CU) + 4 dependent load->ds_write round-trips (~3.6k cyc
//   exposed HBM latency) + barrier + ~2us compute; resident blocks in lockstep.
// R7: grid 3x256; block owns 16 ch x 3584 outputs = 7 segments of 512. Per segment:
//   issue next-seg global loads into regs (58 floats/thread) BEFORE the q-loop ->
//   HBM latency hides under 112 MFMAs; barrier; cvt+ds_write; barrier. A staged once.
//   Compute shape, LDS layout, and all index maps identical to the R6-verified kernel.
//   s_setprio(1) around MFMA cluster (independent blocks at different phases per CU).
// Budget/CU: LDS ~48us, MFMA ~29us, HBM ~52us chip -> expect ~100-125us.

#define T_LEN 10000
#define N_H   413
#define SHIFT 206
#define CB    512            // outputs per segment = 8 pairs of two 32-wide t-tiles
#define BSPAN 3584           // outputs per persistent block = 7 segments
#define ROWH  936            // halfs per e-row (928 staged + 8 pad); stride 468 dw
#define NQ    28             // K-chunks of 16 taps
#define AROWL 472            // halfs per A row: arow[a][r][v] = split(g[v-24-r])

typedef _Float16 v8h   __attribute__((ext_vector_type(8)));
typedef float    v16f  __attribute__((ext_vector_type(16)));
typedef float    v4f   __attribute__((ext_vector_type(4)));
typedef float    f32x2 __attribute__((ext_vector_type(2)));

// Issue global loads for one segment's e-window into registers (no LDS touch).
__device__ __forceinline__ void stage_load(const float* __restrict__ xr, int t0s,
                                           int jt, float sv[4][16]) {
    #pragma unroll
    for (int it = 0; it < 4; ++it) {
        const int c = jt + 16 * it;                  // chunk 0..57 (c>=58 idle)
        if (c < 58) {
            const int j0 = t0s + 16 * c;             // e-index of chunk start
            if (j0 >= SHIFT && j0 + 16 <= T_LEN + SHIFT) {   // interior fast path
                const f32x2* xp = (const f32x2*)(xr + (j0 - SHIFT));   // 8B-aligned
                #pragma unroll
                for (int p = 0; p < 8; ++p) {
                    f32x2 t2 = xp[p]; sv[it][2*p] = t2.x; sv[it][2*p+1] = t2.y;
                }
            } else {                                  // reflect_limited edges
                #pragma unroll
                for (int k = 0; k < 16; ++k) {
                    const int j = j0 + k;
                    float v;
                    if (j < SHIFT)              v = 2.0f * xr[0] - xr[SHIFT - j];
                    else if (j < T_LEN + SHIFT) v = xr[j - SHIFT];
                    else                        v = 2.0f * xr[T_LEN - 1] - xr[2 * T_LEN + SHIFT - 2 - j];
                    // max staged j = 9728 + 927 = 10655 -> mirror idx >= 9549: in-bounds
                    sv[it][k] = v;
                }
            }
        }
    }
}

// Convert staged registers to fp16 and write the e-tile (vmcnt drain lands here).
__device__ __forceinline__ void stage_write(_Float16* __restrict__ erow, int jt,
                                            const float sv[4][16]) {
    #pragma unroll
    for (int it = 0; it < 4; ++it) {
        const int c = jt + 16 * it;
        if (c < 58) {
            v8h h0, h1;
            #pragma unroll
            for (int k = 0; k < 8; ++k) {
                h0[k] = (_Float16)sv[it][k]; h1[k] = (_Float16)sv[it][8 + k];
            }
            *(v8h*)(erow + 16 * c)     = h0;
            *(v8h*)(erow + 16 * c + 8) = h1;
        }
    }
}

__device__ __forceinline__ void store_col(float* __restrict__ orow, const v16f& acc,
                                          int tbase, int guard_needed) {
    // D col = lane&31 -> (ch, th); row m = (reg&3) + 8*(reg>>2) + 4*hh -> t offset.
    #pragma unroll
    for (int g = 0; g < 4; ++g) {
        if (!guard_needed || (tbase + 8 * g) < T_LEN) {
            *(v4f*)(orow + 8 * g) =
                (v4f){acc[4*g], acc[4*g+1], acc[4*g+2], acc[4*g+3]};
        }
    }
}

__global__ __launch_bounds__(256, 3) void FilterBank_20624432955781_kernel(
    const float* __restrict__ x, const float* __restrict__ h, float* __restrict__ out) {
    __shared__ alignas(16) _Float16 lds_e[16 * ROWH];     // 29952 B
    __shared__ alignas(16) _Float16 arow[2][8][AROWL];    // 15104 B (hi, lo)

    const int tid    = threadIdx.x;
    const int t_base = blockIdx.x * BSPAN;                // 0, 3584, 7168
    const int r0     = blockIdx.y * 16;
    const int nseg   = min(7, (T_LEN - t_base + CB - 1) / CB);   // 7, 7, 6

    // ---- stage A ONCE: arow[a][r][v] = split(g[v-24-r]), g[k] = h[412-k] ----
    for (int z = tid; z < 8 * AROWL; z += 256) {
        const int r = z / AROWL, vv = z - r * AROWL;
        const int idx = 436 + r - vv;
        const float gv = (idx >= 0 && idx < N_H) ? h[idx] : 0.0f;
        const _Float16 hi = (_Float16)gv;
        arow[0][r][vv] = hi;
        arow[1][r][vv] = (_Float16)(gv - (float)hi);
    }

    // ---- staging lane constants: 16 threads/row, 58 chunks of 16 floats ----
    const int rr = tid >> 4;
    const int jt = tid & 15;
    const float* __restrict__ xr = x + (size_t)(r0 + rr) * T_LEN;
    _Float16* __restrict__ erow = lds_e + rr * ROWH;

    float sv[4][16];
    stage_load(xr, t_base, jt, sv);                       // segment 0
    stage_write(erow, jt, sv);
    __syncthreads();

    // ---- compute lane constants (identical maps to R6-verified kernel) ----
    const int l  = tid & 63;
    const int wv = tid >> 6;
    const int n  = l & 31;                 // A row m-shift index AND B col (ch, th)
    const int hh = l >> 5;                 // k-half selector
    const int ch = n & 15;
    const int th = n >> 4;
    const int vv0 = 24 + 8 * hh - 8 * (n >> 3);          // in [0,32], 16B-aligned
    const v8h* __restrict__ pah = (const v8h*)(&arow[0][n & 7][0] + vv0);
    const v8h* __restrict__ pal = (const v8h*)(&arow[1][n & 7][0] + vv0);
    const _Float16* __restrict__ ebase = lds_e + ch * ROWH + 32 * th + 8 * hh;
    const _Float16* __restrict__ eb0 = ebase + 64 * wv;        // pair p = wv
    const _Float16* __restrict__ eb1 = ebase + 64 * (wv + 4);  // pair p = wv+4
    float* __restrict__ orow = out + (size_t)(r0 + ch) * T_LEN;

    for (int s = 0; s < nseg; ++s) {
        const int t0s = t_base + s * CB;

        // T14: issue next segment's global loads NOW; they retire under the q-loop.
        if (s + 1 < nseg) stage_load(xr, t0s + CB, jt, sv);

        __builtin_amdgcn_s_setprio(1);
        v16f acc0 = (v16f)(0.0f), acc1 = (v16f)(0.0f);
        #pragma unroll
        for (int q = 0; q < NQ; ++q) {
            const v8h ah = pah[2 * q];                    // g[16q + k - m] (hi)
            const v8h al = pal[2 * q];                    // (lo)
            const v8h b0 = *(const v8h*)(eb0 + 16 * q);
            const v8h b1 = *(const v8h*)(eb1 + 16 * q);
            acc0 = __builtin_amdgcn_mfma_f32_32x32x16_f16(ah, b0, acc0, 0, 0, 0);
            acc1 = __builtin_amdgcn_mfma_f32_32x32x16_f16(ah, b1, acc1, 0, 0, 0);
            acc0 = __builtin_amdgcn_mfma_f32_32x32x16_f16(al, b0, acc0, 0, 0, 0);
            acc1 = __builtin_amdgcn_mfma_f32_32x32x16_f16(al, b1, acc1, 0, 0, 0);
        }
        __builtin_amdgcn_s_setprio(0);

        const int guard = (t0s + CB > T_LEN);             // only last seg of bx=2
        const int tb0 = t0s + 64 * wv + 32 * th + 4 * hh;
        store_col(orow + tb0, acc0, tb0, guard);
        store_col(orow + tb0 + 256, acc1, tb0 + 256, guard);

        if (s + 1 < nseg) {
            __syncthreads();                              // all waves done reading e
            stage_write(erow, jt, sv);                    // vmcnt drain + LDS write
            __syncthreads();                              // e(s+1) visible
        }
    }
}

extern "C" void kernel_launch(void* const* d_in, const int* in_sizes, int n_in,
                              void* d_out, int out_size, void* d_ws, size_t ws_size,
                              hipStream_t stream) {
    const float* x = (const float*)d_in[0];   // [64,64,10000] fp32
    const float* h = (const float*)d_in[1];   // [413] fp32
    float* out = (float*)d_out;               // [64,64,10000] fp32
    dim3 grid(3, 64 * 64 / 16);               // 3 persistent t-thirds x 256 ch-blocks
    FilterBank_20624432955781_kernel<<<grid, dim3(256), 0, stream>>>(x, h, out);
}

// Round 5
// 314.906 us; speedup vs baseline: 1.3184x; 1.0622x over previous
//
#include <hip/hip_runtime.h>

// R8: 8-channel blocks, CB=1024 (8 quads), 4 blocks/CU, vmcnt-clean phase order.
//   out[r, t] = sum_j e[r, j] * g[j - t],  g[k] = h[412-k], e = reflect-extended row.
// R7 post-mortem: 148us with MfmaUtil 20.6 / VALU 5.6 / HBM 29 / Occ 29 -> the three
//   pipe floors (HBM 53us, LDS 48us, MFMA 30us) SUM to ~148: phases serialized. Only
//   3 blocks/CU, lockstep cadence; store-drain exposed in stage_write's vmcnt(0).
// R8 changes:
//   - 8 ch/block; B's 32 cols = (ch, quad-tile): B[k,n] = e[n&7][128Q + 32*(n>>3) + k].
//     LDS 23680(e) + 15104(A) = 38784 B -> 4 blocks/CU (16 waves, ~50% occ), grid
//     2x512 = exactly 4/CU, 5 segments each (balanced).
//   - Per-segment order: load(next)->qloop->barrier->stage_write(next)->stores->barrier:
//     the vmcnt drain before stage_write sees only loads (stores issued after).
//   - Wave owns quads {wv, wv+4}: 2 A + 2 B reads per q (A amortization kept).
//   - All operand/store lane maps identical to the R6/R7-verified kernel.
// Floors unchanged (HBM ~53us, LDS ~47us, MFMA ~30us); 4-block stagger -> ~100-115us.

#define T_LEN 10000
#define N_H   413
#define SHIFT 206
#define CB    1024           // outputs per segment = 8 quads of 128 (4 packed t-tiles)
#define BSPAN 5120           // outputs per persistent block = 5 segments
#define ROWH  1480           // halfs per e-row (1472 staged + 8 pad); 740 dw == 4 mod 32
#define NCHK  92             // 16-half staging chunks per row (92*16 = 1472 = CB+448)
#define NQ    28             // K-chunks of 16 taps
#define AROWL 472            // halfs per A row: arow[a][r][v] = split(g[v-24-r])

typedef _Float16 v8h   __attribute__((ext_vector_type(8)));
typedef float    v16f  __attribute__((ext_vector_type(16)));
typedef float    v4f   __attribute__((ext_vector_type(4)));
typedef float    f32x2 __attribute__((ext_vector_type(2)));

// Issue global loads for one segment's e-window into registers (no LDS touch).
__device__ __forceinline__ void stage_load(const float* __restrict__ xr, int t0s,
                                           int jt, float sv[3][16]) {
    #pragma unroll
    for (int it = 0; it < 3; ++it) {
        const int c = jt + 32 * it;                  // chunk 0..91 (c>=92 idle)
        if (c < NCHK) {
            const int j0 = t0s + 16 * c;             // e-index of chunk start
            if (j0 >= SHIFT && j0 + 16 <= T_LEN + SHIFT) {   // interior fast path
                const f32x2* xp = (const f32x2*)(xr + (j0 - SHIFT));   // 8B-aligned
                #pragma unroll
                for (int p = 0; p < 8; ++p) {
                    f32x2 t2 = xp[p]; sv[it][2*p] = t2.x; sv[it][2*p+1] = t2.y;
                }
            } else {                                  // reflect_limited edges
                #pragma unroll
                for (int k = 0; k < 16; ++k) {
                    const int j = j0 + k;
                    float v;
                    if (j < SHIFT)              v = 2.0f * xr[0] - xr[SHIFT - j];
                    else if (j < T_LEN + SHIFT) v = xr[j - SHIFT];
                    else                        v = 2.0f * xr[T_LEN - 1] - xr[2 * T_LEN + SHIFT - 2 - j];
                    // max staged j = 9216 + 1471 = 10687 -> mirror idx >= 9517: in-bounds;
                    // j > 10411 pairs only with zero-padded g for valid outputs (finite).
                    sv[it][k] = v;
                }
            }
        }
    }
}

// Convert staged registers to fp16 and write the e-tile (vmcnt drain lands here).
__device__ __forceinline__ void stage_write(_Float16* __restrict__ erow, int jt,
                                            const float sv[3][16]) {
    #pragma unroll
    for (int it = 0; it < 3; ++it) {
        const int c = jt + 32 * it;
        if (c < NCHK) {
            v8h h0, h1;
            #pragma unroll
            for (int k = 0; k < 8; ++k) {
                h0[k] = (_Float16)sv[it][k]; h1[k] = (_Float16)sv[it][8 + k];
            }
            *(v8h*)(erow + 16 * c)     = h0;
            *(v8h*)(erow + 16 * c + 8) = h1;
        }
    }
}

__device__ __forceinline__ void store_col(float* __restrict__ orow, const v16f& acc,
                                          int tbase, int guard_needed) {
    // D col = lane&31 -> (ch, tq); row m = (reg&3) + 8*(reg>>2) + 4*hh -> t offset.
    #pragma unroll
    for (int g = 0; g < 4; ++g) {
        if (!guard_needed || (tbase + 8 * g) < T_LEN) {
            *(v4f*)(orow + 8 * g) =
                (v4f){acc[4*g], acc[4*g+1], acc[4*g+2], acc[4*g+3]};
        }
    }
}

__global__ __launch_bounds__(256, 4) void FilterBank_20624432955781_kernel(
    const float* __restrict__ x, const float* __restrict__ h, float* __restrict__ out) {
    __shared__ alignas(16) _Float16 lds_e[8 * ROWH];      // 23680 B
    __shared__ alignas(16) _Float16 arow[2][8][AROWL];    // 15104 B (hi, lo)

    const int tid    = threadIdx.x;
    const int t_base = blockIdx.x * BSPAN;                // 0, 5120
    const int r0     = blockIdx.y * 8;
    const int nseg   = (min(BSPAN, T_LEN - t_base) + CB - 1) / CB;   // 5, 5

    // ---- stage A ONCE: arow[a][r][v] = split(g[v-24-r]), g[k] = h[412-k] ----
    for (int z = tid; z < 8 * AROWL; z += 256) {
        const int r = z / AROWL, vv = z - r * AROWL;
        const int idx = 436 + r - vv;
        const float gv = (idx >= 0 && idx < N_H) ? h[idx] : 0.0f;
        const _Float16 hi = (_Float16)gv;
        arow[0][r][vv] = hi;
        arow[1][r][vv] = (_Float16)(gv - (float)hi);
    }

    // ---- staging lane constants: 32 threads/row, 92 chunks of 16 floats ----
    const int rr = tid >> 5;                              // row 0..7
    const int jt = tid & 31;
    const float* __restrict__ xr = x + (size_t)(r0 + rr) * T_LEN;
    _Float16* __restrict__ erow = lds_e + rr * ROWH;

    float sv[3][16];
    stage_load(xr, t_base, jt, sv);                       // segment 0
    stage_write(erow, jt, sv);
    __syncthreads();

    // ---- compute lane constants (identical maps to R6/R7-verified kernel) ----
    const int l  = tid & 63;
    const int wv = tid >> 6;
    const int n  = l & 31;                 // A row m-shift index AND B col (ch, tq)
    const int hh = l >> 5;                 // k-half selector
    const int ch = n & 7;
    const int tq = n >> 3;
    const int vv0 = 24 + 8 * hh - 8 * tq;                 // in [0,32], 16B-aligned
    const v8h* __restrict__ pah = (const v8h*)(&arow[0][n & 7][0] + vv0);
    const v8h* __restrict__ pal = (const v8h*)(&arow[1][n & 7][0] + vv0);
    const _Float16* __restrict__ ebase = lds_e + ch * ROWH + 32 * tq + 8 * hh;
    const _Float16* __restrict__ eb0 = ebase + 128 * wv;        // quad Q0 = wv
    const _Float16* __restrict__ eb1 = ebase + 128 * (wv + 4);  // quad Q1 = wv+4
    float* __restrict__ orow = out + (size_t)(r0 + ch) * T_LEN;

    for (int s = 0; s < nseg; ++s) {
        const int t0s = t_base + s * CB;
        const int last = (s + 1 == nseg);

        // T14: issue next segment's global loads NOW; they retire under the q-loop.
        if (!last) stage_load(xr, t0s + CB, jt, sv);

        const int NQd = min(8, (T_LEN - t0s + 127) >> 7); // quads this segment (8 or 7)
        const int dual = (wv + 4 < NQd);

        __builtin_amdgcn_s_setprio(1);
        v16f acc0 = (v16f)(0.0f), acc1 = (v16f)(0.0f);
        if (dual) {
            #pragma unroll
            for (int q = 0; q < NQ; ++q) {
                const v8h ah = pah[2 * q];                // g[16q + k - m] (hi)
                const v8h al = pal[2 * q];                // (lo)
                const v8h b0 = *(const v8h*)(eb0 + 16 * q);
                const v8h b1 = *(const v8h*)(eb1 + 16 * q);
                acc0 = __builtin_amdgcn_mfma_f32_32x32x16_f16(ah, b0, acc0, 0, 0, 0);
                acc1 = __builtin_amdgcn_mfma_f32_32x32x16_f16(ah, b1, acc1, 0, 0, 0);
                acc0 = __builtin_amdgcn_mfma_f32_32x32x16_f16(al, b0, acc0, 0, 0, 0);
                acc1 = __builtin_amdgcn_mfma_f32_32x32x16_f16(al, b1, acc1, 0, 0, 0);
            }
        } else {
            #pragma unroll
            for (int q = 0; q < NQ; ++q) {
                const v8h ah = pah[2 * q];
                const v8h al = pal[2 * q];
                const v8h b0 = *(const v8h*)(eb0 + 16 * q);
                acc0 = __builtin_amdgcn_mfma_f32_32x32x16_f16(ah, b0, acc0, 0, 0, 0);
                acc0 = __builtin_amdgcn_mfma_f32_32x32x16_f16(al, b0, acc0, 0, 0, 0);
            }
        }
        __builtin_amdgcn_s_setprio(0);

        if (!last) {
            __syncthreads();                  // all waves done reading e(s)
            stage_write(erow, jt, sv);        // vmcnt wait sees ONLY loads outstanding
        }

        // stores issued AFTER stage_write -> never block a vmcnt drain
        {
            const int tb0 = t0s + 128 * wv + 32 * tq + 4 * hh;
            store_col(orow + tb0, acc0, tb0, (t0s + 128 * wv + 128) > T_LEN);
            if (dual) {
                const int tb1 = tb0 + 512;
                store_col(orow + tb1, acc1, tb1, (t0s + 128 * (wv + 4) + 128) > T_LEN);
            }
        }

        if (!last) __syncthreads();           // e(s+1) visible before next q-loop
    }
}

extern "C" void kernel_launch(void* const* d_in, const int* in_sizes, int n_in,
                              void* d_out, int out_size, void* d_ws, size_t ws_size,
                              hipStream_t stream) {
    const float* x = (const float*)d_in[0];   // [64,64,10000] fp32
    const float* h = (const float*)d_in[1];   // [413] fp32
    float* out = (float*)d_out;               // [64,64,10000] fp32
    dim3 grid(2, 64 * 64 / 8);                // 2 t-halves x 512 channel-blocks = 4/CU
    FilterBank_20624432955781_kernel<<<grid, dim3(256), 0, stream>>>(x, h, out);
}